// Round 1
// baseline (4999.457 us; speedup 1.0000x reference)
//
#include <hip/hip_runtime.h>
#include <hip/hip_bf16.h>
#include <math.h>

#define B_      2
#define S_      2048
#define HID_    2048
#define H_      16
#define D_NOPE_ 128
#define D_ROPE_ 64
#define D_V_    128
#define R_      512
#define D_Q_    192
#define NTOK    (B_ * S_)
#define EPS_    1e-6f

// ---------------------------------------------------------------------------
// Generic f32 GEMM: C[M,N] = A[M,K] @ B[K,N], row-major.
// Requires M%64==0, N%64==0, K%16==0 (true for all 4 call sites).
// 64x64 block tile, 256 threads, 4x4 microtile, BK=16.
// ---------------------------------------------------------------------------
__global__ __launch_bounds__(256) void gemm_f32(const float* __restrict__ A,
                                                const float* __restrict__ Bm,
                                                float* __restrict__ C,
                                                int M, int N, int K) {
    __shared__ float As[16][68];   // [k][m], pad 68 -> 2-way write conflict (free)
    __shared__ float Bs[16][64];   // [k][n]

    const int tid = threadIdx.x;
    const int tx = tid & 15, ty = tid >> 4;
    const int brow = blockIdx.y * 64, bcol = blockIdx.x * 64;

    const int arow = tid >> 2;          // 0..63
    const int akq  = (tid & 3) * 4;     // 0,4,8,12
    const int bk   = tid >> 4;          // 0..15
    const int bn   = (tid & 15) * 4;    // 0..60

    const float* Aptr = A + (size_t)(brow + arow) * K + akq;
    const float* Bptr = Bm + (size_t)bk * N + bcol + bn;

    float acc[4][4] = {};

    for (int k0 = 0; k0 < K; k0 += 16) {
        float4 av = *(const float4*)(Aptr + k0);
        float4 bv = *(const float4*)(Bptr + (size_t)k0 * N);
        As[akq + 0][arow] = av.x;
        As[akq + 1][arow] = av.y;
        As[akq + 2][arow] = av.z;
        As[akq + 3][arow] = av.w;
        *(float4*)&Bs[bk][bn] = bv;
        __syncthreads();
#pragma unroll
        for (int k = 0; k < 16; ++k) {
            float4 a = *(const float4*)&As[k][ty * 4];
            float4 b = *(const float4*)&Bs[k][tx * 4];
            acc[0][0] += a.x * b.x; acc[0][1] += a.x * b.y; acc[0][2] += a.x * b.z; acc[0][3] += a.x * b.w;
            acc[1][0] += a.y * b.x; acc[1][1] += a.y * b.y; acc[1][2] += a.y * b.z; acc[1][3] += a.y * b.w;
            acc[2][0] += a.z * b.x; acc[2][1] += a.z * b.y; acc[2][2] += a.z * b.z; acc[2][3] += a.z * b.w;
            acc[3][0] += a.w * b.x; acc[3][1] += a.w * b.y; acc[3][2] += a.w * b.z; acc[3][3] += a.w * b.w;
        }
        __syncthreads();
    }

#pragma unroll
    for (int i = 0; i < 4; ++i) {
        float4 v = make_float4(acc[i][0], acc[i][1], acc[i][2], acc[i][3]);
        *(float4*)&C[(size_t)(brow + ty * 4 + i) * N + bcol + tx * 4] = v;
    }
}

// ---------------------------------------------------------------------------
// RoPE on q_pe (last 64 dims of each head's 192), in place.
// One thread per (token, head, pair i<32).
// ---------------------------------------------------------------------------
__global__ __launch_bounds__(256) void rope_q(float* __restrict__ q,
                                              const float* __restrict__ cosT,
                                              const float* __restrict__ sinT,
                                              const int* __restrict__ pid) {
    int g = blockIdx.x * 256 + threadIdx.x;      // NTOK*H*32 total
    int i = g & 31;
    int h = (g >> 5) & (H_ - 1);
    int tok = g >> 9;
    int pos = pid[tok];
    float c = cosT[pos * 32 + i];
    float s = sinT[pos * 32 + i];
    float* base = q + (size_t)tok * (H_ * D_Q_) + h * D_Q_ + D_NOPE_;
    float x1 = base[i];
    float x2 = base[i + 32];
    base[i]      = x1 * c - x2 * s;
    base[i + 32] = x2 * c + x1 * s;
}

// ---------------------------------------------------------------------------
// Per-token: LayerNorm over first 512 of ckv -> kvcn; RoPE last 64 -> kpe.
// One 256-thread block per token.
// ---------------------------------------------------------------------------
__global__ __launch_bounds__(256) void ln_rope(const float* __restrict__ ckv,
                                               const float* __restrict__ g,
                                               const float* __restrict__ bb,
                                               const float* __restrict__ cosT,
                                               const float* __restrict__ sinT,
                                               const int* __restrict__ pid,
                                               float* __restrict__ kvcn,
                                               float* __restrict__ kpe) {
    int tok = blockIdx.x;
    int tid = threadIdx.x;
    const float* x = ckv + (size_t)tok * 576;

    float v0 = x[tid], v1 = x[tid + 256];
    float s = v0 + v1, sq = v0 * v0 + v1 * v1;
#pragma unroll
    for (int m = 1; m < 64; m <<= 1) {
        s  += __shfl_xor(s, m);
        sq += __shfl_xor(sq, m);
    }
    __shared__ float ws[8];
    int wid = tid >> 6, lane = tid & 63;
    if (lane == 0) { ws[wid] = s; ws[4 + wid] = sq; }
    __syncthreads();
    s  = ws[0] + ws[1] + ws[2] + ws[3];
    sq = ws[4] + ws[5] + ws[6] + ws[7];
    float mean = s * (1.f / 512.f);
    float var  = sq * (1.f / 512.f) - mean * mean;
    float rstd = rsqrtf(var + EPS_);

    kvcn[(size_t)tok * 512 + tid]       = (v0 - mean) * rstd * g[tid]       + bb[tid];
    kvcn[(size_t)tok * 512 + tid + 256] = (v1 - mean) * rstd * g[tid + 256] + bb[tid + 256];

    if (tid < 32) {
        int pos = pid[tok];
        float c  = cosT[pos * 32 + tid];
        float sn = sinT[pos * 32 + tid];
        float x1 = x[512 + tid];
        float x2 = x[512 + 32 + tid];
        kpe[(size_t)tok * 64 + tid]      = x1 * c - x2 * sn;
        kpe[(size_t)tok * 64 + 32 + tid] = x2 * c + x1 * sn;
    }
}

// ---------------------------------------------------------------------------
// Causal flash attention, f32. Block = (16 queries) x (one b,h). 256 threads.
// Key tiles of 32. K = concat(k_nope[128], k_pe[64]); V = kv[...,128:256].
// Thread (r = tid/16, c = tid%16): scores for cols c, c+16; output dims c+16*dd.
// ---------------------------------------------------------------------------
__global__ __launch_bounds__(256) void flash_attn(const float* __restrict__ q,
                                                  const float* __restrict__ kv,
                                                  const float* __restrict__ kpe,
                                                  float* __restrict__ attno) {
    __shared__ float Qs[16][196];
    __shared__ float Ks[32][196];
    __shared__ float Vs[32][128];
    __shared__ float Ps[16][33];

    const int q0 = blockIdx.x * 16;
    const int h = blockIdx.y;
    const int b = blockIdx.z;
    const int tid = threadIdx.x;
    const float scale = 0.07216878364870323f;  // 1/sqrt(192)

    for (int t = tid; t < 16 * 192; t += 256) {
        int r = t / 192, d = t % 192;
        Qs[r][d] = q[((size_t)(b * S_ + q0 + r) * H_ + h) * D_Q_ + d] * scale;
    }

    const int r = tid >> 4, c = tid & 15;
    float m_r = -INFINITY, l_r = 0.f;
    float acc[8] = {};

    const int ktmax = (q0 + 15) / 32;
    for (int kt = 0; kt <= ktmax; ++kt) {
        const int k0 = kt * 32;
        __syncthreads();   // prev PV done (also covers Q load on first iter)
        for (int t = tid; t < 32 * 192; t += 256) {
            int j = t / 192, d = t % 192;
            float val = (d < 128)
                ? kv[((size_t)(b * S_ + k0 + j) * H_ + h) * 256 + d]
                : kpe[(size_t)(b * S_ + k0 + j) * 64 + (d - 128)];
            Ks[j][d] = val;
        }
        for (int t = tid; t < 32 * 128; t += 256) {
            int j = t >> 7, d = t & 127;
            Vs[j][d] = kv[((size_t)(b * S_ + k0 + j) * H_ + h) * 256 + 128 + d];
        }
        __syncthreads();

        float s0 = 0.f, s1 = 0.f;
#pragma unroll 4
        for (int d4 = 0; d4 < 192; d4 += 4) {
            float4 qv  = *(const float4*)&Qs[r][d4];
            float4 k0v = *(const float4*)&Ks[c][d4];
            float4 k1v = *(const float4*)&Ks[c + 16][d4];
            s0 += qv.x * k0v.x + qv.y * k0v.y + qv.z * k0v.z + qv.w * k0v.w;
            s1 += qv.x * k1v.x + qv.y * k1v.y + qv.z * k1v.z + qv.w * k1v.w;
        }
        if (k0 + c > q0 + r) s0 = -INFINITY;
        if (k0 + c + 16 > q0 + r) s1 = -INFINITY;

        float tm = fmaxf(s0, s1);
#pragma unroll
        for (int m = 1; m < 16; m <<= 1) tm = fmaxf(tm, __shfl_xor(tm, m));
        float m_new = fmaxf(m_r, tm);
        float p0 = __expf(s0 - m_new);
        float p1 = __expf(s1 - m_new);
        float rs = p0 + p1;
#pragma unroll
        for (int m = 1; m < 16; m <<= 1) rs += __shfl_xor(rs, m);
        float alpha = __expf(m_r - m_new);
        l_r = l_r * alpha + rs;
        m_r = m_new;
        Ps[r][c] = p0;
        Ps[r][c + 16] = p1;
#pragma unroll
        for (int dd = 0; dd < 8; ++dd) acc[dd] *= alpha;
        __syncthreads();

        for (int j = 0; j < 32; ++j) {
            float p = Ps[r][j];
#pragma unroll
            for (int dd = 0; dd < 8; ++dd)
                acc[dd] += p * Vs[j][c + 16 * dd];
        }
    }

    float inv = 1.f / l_r;
#pragma unroll
    for (int dd = 0; dd < 8; ++dd)
        attno[((size_t)(b * S_ + q0 + r) * H_ + h) * D_V_ + c + 16 * dd] = acc[dd] * inv;
}

// ---------------------------------------------------------------------------
extern "C" void kernel_launch(void* const* d_in, const int* in_sizes, int n_in,
                              void* d_out, int out_size, void* d_ws, size_t ws_size,
                              hipStream_t stream) {
    const float* hidden = (const float*)d_in[0];
    const float* cosT   = (const float*)d_in[1];
    const float* sinT   = (const float*)d_in[2];
    const int*   pid    = (const int*)d_in[3];
    const float* Wq     = (const float*)d_in[4];
    const float* Wkv_a  = (const float*)d_in[5];
    const float* ln_g   = (const float*)d_in[6];
    const float* ln_b   = (const float*)d_in[7];
    const float* Wkv_b  = (const float*)d_in[8];
    const float* Wo     = (const float*)d_in[9];
    float* out = (float*)d_out;

    float* ws   = (float*)d_ws;
    float* q     = ws;                                  // NTOK*H*192  = 12.58M
    float* ckv   = q     + (size_t)NTOK * H_ * D_Q_;    // NTOK*576    =  2.36M
    float* kvcn  = ckv   + (size_t)NTOK * 576;          // NTOK*512    =  2.10M
    float* kpe   = kvcn  + (size_t)NTOK * R_;           // NTOK*64     =  0.26M
    float* kvb   = kpe   + (size_t)NTOK * D_ROPE_;      // NTOK*H*256  = 16.78M
    float* attno = kvb   + (size_t)NTOK * H_ * 256;     // NTOK*H*128  =  8.39M

    // 1. q = hidden @ Wq                (4096 x 3072, K=2048)
    gemm_f32<<<dim3(3072 / 64, NTOK / 64), 256, 0, stream>>>(hidden, Wq, q, NTOK, 3072, 2048);
    // 2. RoPE(q_pe) in place
    rope_q<<<(NTOK * H_ * 32) / 256, 256, 0, stream>>>(q, cosT, sinT, pid);
    // 3. ckv = hidden @ Wkv_a           (4096 x 576, K=2048)
    gemm_f32<<<dim3(576 / 64, NTOK / 64), 256, 0, stream>>>(hidden, Wkv_a, ckv, NTOK, 576, 2048);
    // 4. LayerNorm + RoPE(k_pe)
    ln_rope<<<NTOK, 256, 0, stream>>>(ckv, ln_g, ln_b, cosT, sinT, pid, kvcn, kpe);
    // 5. kv = kvcn @ Wkv_b              (4096 x 4096, K=512)
    gemm_f32<<<dim3(4096 / 64, NTOK / 64), 256, 0, stream>>>(kvcn, Wkv_b, kvb, NTOK, 4096, 512);
    // 6. causal flash attention
    flash_attn<<<dim3(S_ / 16, H_, B_), 256, 0, stream>>>(q, kvb, kpe, attno);
    // 7. out = attno @ Wo               (4096 x 2048, K=2048)
    gemm_f32<<<dim3(2048 / 64, NTOK / 64), 256, 0, stream>>>(attno, Wo, out, NTOK, 2048, 2048);
}

// Round 3
// 968.454 us; speedup vs baseline: 5.1623x; 5.1623x over previous
//
#include <hip/hip_runtime.h>
#include <math.h>
#include <stdint.h>

#define B_      2
#define S_      2048
#define HID_    2048
#define H_      16
#define D_NOPE_ 128
#define D_ROPE_ 64
#define D_V_    128
#define R_      512
#define D_Q_    192
#define NTOK    (B_ * S_)
#define EPS_    1e-6f

typedef __attribute__((ext_vector_type(8))) short bf16x8;
typedef __attribute__((ext_vector_type(4))) float f32x4;

__device__ __forceinline__ short f2bf(float x) {
    union { float f; unsigned u; } un; un.f = x;
    unsigned r = (un.u + 0x7fffu + ((un.u >> 16) & 1u)) >> 16;
    return (short)r;
}

__device__ __forceinline__ void async_ld16(const short* gsrc, short* ldst) {
    __builtin_amdgcn_global_load_lds(
        (const __attribute__((address_space(1))) void*)gsrc,
        (__attribute__((address_space(3))) void*)ldst, 16, 0, 0);
}

// ---------------------------------------------------------------------------
// cast f32 -> bf16, n must be multiple of 1024 (grid covers exactly)
// ---------------------------------------------------------------------------
__global__ __launch_bounds__(256) void castk(const float* __restrict__ in, short* __restrict__ out) {
    int i = blockIdx.x * 256 + threadIdx.x;
    float4 v = ((const float4*)in)[i];
    ushort4 o;
    o.x = (unsigned short)f2bf(v.x); o.y = (unsigned short)f2bf(v.y);
    o.z = (unsigned short)f2bf(v.z); o.w = (unsigned short)f2bf(v.w);
    ((ushort4*)out)[i] = o;
}

// ---------------------------------------------------------------------------
// W[K][Nreal] f32 -> WT[Npad][K] bf16 (rows >= Nreal zero-filled).
// grid (Npad/32, K/32), 256 threads.
// ---------------------------------------------------------------------------
__global__ __launch_bounds__(256) void transpose_cast(const float* __restrict__ W,
                                                      short* __restrict__ WT,
                                                      int K, int Nreal) {
    __shared__ float T[32][33];
    const int n0 = blockIdx.x * 32, k0 = blockIdx.y * 32;
    const int t = threadIdx.x;
    const int r = t >> 3, c4 = (t & 7) * 4;
    float4 v = make_float4(0.f, 0.f, 0.f, 0.f);
    if (n0 < Nreal) v = *(const float4*)&W[(size_t)(k0 + r) * Nreal + n0 + c4];
    T[r][c4 + 0] = v.x; T[r][c4 + 1] = v.y; T[r][c4 + 2] = v.z; T[r][c4 + 3] = v.w;
    __syncthreads();
    const int n = t >> 3, k4 = (t & 7) * 4;
    ushort4 o;
    o.x = (unsigned short)f2bf(T[k4 + 0][n]);
    o.y = (unsigned short)f2bf(T[k4 + 1][n]);
    o.z = (unsigned short)f2bf(T[k4 + 2][n]);
    o.w = (unsigned short)f2bf(T[k4 + 3][n]);
    *(ushort4*)&WT[(size_t)(n0 + n) * K + k0 + k4] = o;
}

// ---------------------------------------------------------------------------
// MFMA GEMM: C[M][N] = A[M][K](bf16) @ BT[N][K](bf16).  M%128==0, N%128==0,
// K%32==0.  128x128 tile, 4 waves (2x2), 16x16x32 MFMA, global_load_lds
// staging with XOR-swizzled source (rule 21).
// ---------------------------------------------------------------------------
template <int OUTBF>
__global__ __launch_bounds__(256) void gemm_mfma(const short* __restrict__ A,
                                                 const short* __restrict__ BT,
                                                 void* __restrict__ C,
                                                 int M, int N, int K) {
    __shared__ short As[128 * 32];
    __shared__ short Bs[128 * 32];
    const int tid = threadIdx.x;
    const int lane = tid & 63, w = tid >> 6;
    const int brow = blockIdx.y * 128, bcol = blockIdx.x * 128;

    // staging: issue i covers LDS bytes [w*1024 + i*4096 + lane*16, +16)
    const int o0 = w * 1024 + lane * 16;
    const int r0 = o0 >> 6, q0p = (o0 >> 4) & 3;
    const int o1 = o0 + 4096;
    const int r1 = o1 >> 6, q1p = (o1 >> 4) & 3;
    const int s0 = r0 * K + 8 * (q0p ^ ((r0 >> 1) & 3));
    const int s1 = r1 * K + 8 * (q1p ^ ((r1 >> 1) & 3));
    const short* Ab = A + (size_t)brow * K;
    const short* Bb = BT + (size_t)bcol * K;
    short* AsU0 = &As[w * 512]; short* AsU1 = &As[w * 512 + 2048];
    short* BsU0 = &Bs[w * 512]; short* BsU1 = &Bs[w * 512 + 2048];

    const int wr = w >> 1, wc = w & 1;
    const int c16 = lane & 15, g = lane >> 4;
    const int qph = (g ^ ((c16 >> 1) & 3)) * 8;   // physical 8-elem block for reads

    f32x4 zero = {0.f, 0.f, 0.f, 0.f};
    f32x4 acc[4][4];
#pragma unroll
    for (int i = 0; i < 4; ++i)
#pragma unroll
        for (int j = 0; j < 4; ++j) acc[i][j] = zero;

    for (int k0 = 0; k0 < K; k0 += 32) {
        async_ld16(Ab + s0 + k0, AsU0);
        async_ld16(Ab + s1 + k0, AsU1);
        async_ld16(Bb + s0 + k0, BsU0);
        async_ld16(Bb + s1 + k0, BsU1);
        __syncthreads();
        bf16x8 af[4], bf[4];
#pragma unroll
        for (int i = 0; i < 4; ++i) {
            af[i] = *(const bf16x8*)&As[(wr * 64 + i * 16 + c16) * 32 + qph];
            bf[i] = *(const bf16x8*)&Bs[(wc * 64 + i * 16 + c16) * 32 + qph];
        }
#pragma unroll
        for (int mi = 0; mi < 4; ++mi)
#pragma unroll
            for (int ni = 0; ni < 4; ++ni)
                acc[mi][ni] = __builtin_amdgcn_mfma_f32_16x16x32_bf16(af[mi], bf[ni], acc[mi][ni], 0, 0, 0);
        __syncthreads();
    }

#pragma unroll
    for (int mi = 0; mi < 4; ++mi)
#pragma unroll
        for (int ni = 0; ni < 4; ++ni)
#pragma unroll
            for (int reg = 0; reg < 4; ++reg) {
                int row = brow + wr * 64 + mi * 16 + 4 * g + reg;
                int col = bcol + wc * 64 + ni * 16 + c16;
                if (OUTBF) ((short*)C)[(size_t)row * N + col] = f2bf(acc[mi][ni][reg]);
                else       ((float*)C)[(size_t)row * N + col] = acc[mi][ni][reg];
            }
}

// ---------------------------------------------------------------------------
// RoPE q_pe + cast all of q to bf16. One block per token.
// ---------------------------------------------------------------------------
__global__ __launch_bounds__(256) void rope_cast_q(const float* __restrict__ q,
                                                   short* __restrict__ qb,
                                                   const float* __restrict__ cosT,
                                                   const float* __restrict__ sinT,
                                                   const int* __restrict__ pid) {
    const int tok = blockIdx.x, t = threadIdx.x;
    const float* src = q + (size_t)tok * 3072;
    short* dst = qb + (size_t)tok * 3072;
    // nope cast: h = t>>4, d0 = (t&15)*8
    {
        int h = t >> 4, d0 = (t & 15) * 8;
        const float* s1 = src + h * 192 + d0;
        float4 a = *(const float4*)s1;
        float4 b = *(const float4*)(s1 + 4);
        ushort4 o1, o2;
        o1.x = (unsigned short)f2bf(a.x); o1.y = (unsigned short)f2bf(a.y);
        o1.z = (unsigned short)f2bf(a.z); o1.w = (unsigned short)f2bf(a.w);
        o2.x = (unsigned short)f2bf(b.x); o2.y = (unsigned short)f2bf(b.y);
        o2.z = (unsigned short)f2bf(b.z); o2.w = (unsigned short)f2bf(b.w);
        *(ushort4*)(dst + h * 192 + d0) = o1;
        *(ushort4*)(dst + h * 192 + d0 + 4) = o2;
    }
    const int pos = pid[tok];
#pragma unroll
    for (int pp = 0; pp < 2; ++pp) {
        int p = t * 2 + pp;                 // 0..511
        int h2 = p >> 5, i = p & 31;
        float cc = cosT[pos * 32 + i], ss = sinT[pos * 32 + i];
        float x1 = src[h2 * 192 + 128 + i], x2 = src[h2 * 192 + 160 + i];
        dst[h2 * 192 + 128 + i] = f2bf(x1 * cc - x2 * ss);
        dst[h2 * 192 + 160 + i] = f2bf(x2 * cc + x1 * ss);
    }
}

// ---------------------------------------------------------------------------
// LayerNorm(512) + RoPE(k_pe). ckv stride 640. Outputs bf16.
// ---------------------------------------------------------------------------
__global__ __launch_bounds__(256) void ln_rope(const float* __restrict__ ckv,
                                               const float* __restrict__ gam,
                                               const float* __restrict__ bet,
                                               const float* __restrict__ cosT,
                                               const float* __restrict__ sinT,
                                               const int* __restrict__ pid,
                                               short* __restrict__ kvcn,
                                               short* __restrict__ kpe) {
    const int tok = blockIdx.x, tid = threadIdx.x;
    const float* x = ckv + (size_t)tok * 640;
    float v0 = x[tid], v1 = x[tid + 256];
    float s = v0 + v1, sq = v0 * v0 + v1 * v1;
#pragma unroll
    for (int m = 1; m < 64; m <<= 1) { s += __shfl_xor(s, m); sq += __shfl_xor(sq, m); }
    __shared__ float ws[8];
    int wid = tid >> 6, lane = tid & 63;
    if (lane == 0) { ws[wid] = s; ws[4 + wid] = sq; }
    __syncthreads();
    s = ws[0] + ws[1] + ws[2] + ws[3];
    sq = ws[4] + ws[5] + ws[6] + ws[7];
    float mean = s * (1.f / 512.f);
    float var = sq * (1.f / 512.f) - mean * mean;
    float rstd = rsqrtf(var + EPS_);
    kvcn[(size_t)tok * 512 + tid]       = f2bf((v0 - mean) * rstd * gam[tid] + bet[tid]);
    kvcn[(size_t)tok * 512 + tid + 256] = f2bf((v1 - mean) * rstd * gam[tid + 256] + bet[tid + 256]);
    if (tid < 32) {
        int pos = pid[tok];
        float c = cosT[pos * 32 + tid], sn = sinT[pos * 32 + tid];
        float x1 = x[512 + tid], x2 = x[512 + 32 + tid];
        kpe[(size_t)tok * 64 + tid]      = f2bf(x1 * c - x2 * sn);
        kpe[(size_t)tok * 64 + 32 + tid] = f2bf(x2 * c + x1 * sn);
    }
}

// ---------------------------------------------------------------------------
// V transpose: kvb[token][h][128..255] -> Vt[b][h][d][s]. grid (S/64, 2, B*H)
// ---------------------------------------------------------------------------
__global__ __launch_bounds__(256) void transpose_v(const short* __restrict__ kvb,
                                                   short* __restrict__ Vt) {
    __shared__ short T[64][72];
    const int s0 = blockIdx.x * 64, d0 = blockIdx.y * 64, bh = blockIdx.z;
    const int b = bh >> 4, h = bh & 15;
    const int t = threadIdx.x;
    const int r = t >> 3, c8 = (t & 7) * 8;
#pragma unroll
    for (int i = 0; i < 2; ++i) {
        int rr = r + 32 * i;
        bf16x8 v = *(const bf16x8*)&kvb[((size_t)(b * 2048 + s0 + rr) * 16 + h) * 256 + 128 + d0 + c8];
        *(bf16x8*)&T[rr][c8] = v;
    }
    __syncthreads();
#pragma unroll
    for (int i = 0; i < 2; ++i) {
        int d = r + 32 * i;
        bf16x8 o;
#pragma unroll
        for (int j = 0; j < 8; ++j) o[j] = T[c8 + j][d];
        *(bf16x8*)&Vt[((size_t)(b * 16 + h) * 128 + d0 + d) * 2048 + s0 + c8] = o;
    }
}

// ---------------------------------------------------------------------------
// MFMA flash attention. Block = 64 q-rows (4 waves x 16), one (b,h).
// KV tiles of 64. K/V fragments straight from global (L2-resident).
// ---------------------------------------------------------------------------
__global__ __launch_bounds__(256) void flash_mfma(const short* __restrict__ qb,
                                                  const short* __restrict__ kvb,
                                                  const short* __restrict__ kpe,
                                                  const short* __restrict__ Vt,
                                                  short* __restrict__ attno) {
    const int q0 = blockIdx.x * 64;
    const int h = blockIdx.y, b = blockIdx.z;
    const int tid = threadIdx.x, lane = tid & 63, w = tid >> 6;
    const int c16 = lane & 15, g = lane >> 4, g8 = g * 8;
    const float scale = 0.07216878364870323f;   // 1/sqrt(192)
    __shared__ short P[4][16][72];

    const int qrow = q0 + w * 16;
    const size_t qbase = ((size_t)(b * 2048 + qrow + c16) * 16 + h) * 192 + g8;
    bf16x8 qf[6];
#pragma unroll
    for (int ks = 0; ks < 6; ++ks) qf[ks] = *(const bf16x8*)(qb + qbase + 32 * ks);

    f32x4 zero = {0.f, 0.f, 0.f, 0.f};
    f32x4 acc[8];
#pragma unroll
    for (int i = 0; i < 8; ++i) acc[i] = zero;
    float mreg[4] = {-INFINITY, -INFINITY, -INFINITY, -INFINITY};
    float lreg[4] = {0.f, 0.f, 0.f, 0.f};

    const int nt = q0 / 64 + 1;
    for (int kt = 0; kt < nt; ++kt) {
        const int k0 = kt * 64;
        f32x4 sc[4];
#pragma unroll
        for (int i = 0; i < 4; ++i) sc[i] = zero;

        // QK^T: nope part (kvb token stride 16*256=4096 shorts, d = g8 + ks*32)
        const size_t kb = ((size_t)(b * 2048 + k0 + c16) * 16 + h) * 256 + g8;
#pragma unroll
        for (int ks = 0; ks < 4; ++ks)
#pragma unroll
            for (int nb = 0; nb < 4; ++nb) {
                bf16x8 kf = *(const bf16x8*)(kvb + kb + (size_t)nb * 16 * 4096 + ks * 32);
                sc[nb] = __builtin_amdgcn_mfma_f32_16x16x32_bf16(qf[ks], kf, sc[nb], 0, 0, 0);
            }
        const size_t pb = (size_t)(b * 2048 + k0 + c16) * 64 + g8;
#pragma unroll
        for (int ks = 0; ks < 2; ++ks)
#pragma unroll
            for (int nb = 0; nb < 4; ++nb) {
                bf16x8 kf = *(const bf16x8*)(kpe + pb + (size_t)nb * 16 * 64 + ks * 32);
                sc[nb] = __builtin_amdgcn_mfma_f32_16x16x32_bf16(qf[4 + ks], kf, sc[nb], 0, 0, 0);
            }

#pragma unroll
        for (int nb = 0; nb < 4; ++nb) sc[nb] *= scale;

        if (kt == nt - 1) {
#pragma unroll
            for (int nb = 0; nb < 4; ++nb)
#pragma unroll
                for (int reg = 0; reg < 4; ++reg) {
                    int col = k0 + nb * 16 + c16;
                    int row = qrow + 4 * g + reg;
                    if (col > row) sc[nb][reg] = -INFINITY;
                }
        }

        // online softmax (rows = 4g+reg, reduce over 16 lanes of the group)
        float rmax[4], rsum[4], mnew[4], alpha[4];
#pragma unroll
        for (int reg = 0; reg < 4; ++reg)
            rmax[reg] = fmaxf(fmaxf(sc[0][reg], sc[1][reg]), fmaxf(sc[2][reg], sc[3][reg]));
#pragma unroll
        for (int m = 1; m < 16; m <<= 1)
#pragma unroll
            for (int reg = 0; reg < 4; ++reg)
                rmax[reg] = fmaxf(rmax[reg], __shfl_xor(rmax[reg], m));
#pragma unroll
        for (int reg = 0; reg < 4; ++reg) {
            mnew[reg] = fmaxf(mreg[reg], rmax[reg]);
            alpha[reg] = __expf(mreg[reg] - mnew[reg]);
            mreg[reg] = mnew[reg];
            rsum[reg] = 0.f;
        }
#pragma unroll
        for (int nb = 0; nb < 4; ++nb)
#pragma unroll
            for (int reg = 0; reg < 4; ++reg) {
                float p = __expf(sc[nb][reg] - mnew[reg]);
                sc[nb][reg] = p;
                rsum[reg] += p;
            }
#pragma unroll
        for (int m = 1; m < 16; m <<= 1)
#pragma unroll
            for (int reg = 0; reg < 4; ++reg)
                rsum[reg] += __shfl_xor(rsum[reg], m);
#pragma unroll
        for (int reg = 0; reg < 4; ++reg) lreg[reg] = lreg[reg] * alpha[reg] + rsum[reg];
#pragma unroll
        for (int nb = 0; nb < 8; ++nb)
#pragma unroll
            for (int reg = 0; reg < 4; ++reg) acc[nb][reg] *= alpha[reg];

        // P -> LDS (C/D layout -> A layout roundtrip)
#pragma unroll
        for (int nb = 0; nb < 4; ++nb)
#pragma unroll
            for (int reg = 0; reg < 4; ++reg)
                P[w][4 * g + reg][nb * 16 + c16] = f2bf(sc[nb][reg]);

        // PV
        const size_t vb = ((size_t)(b * 16 + h) * 128 + c16) * 2048 + k0 + g8;
#pragma unroll
        for (int ks = 0; ks < 2; ++ks) {
            bf16x8 pf = *(const bf16x8*)&P[w][c16][ks * 32 + g8];
#pragma unroll
            for (int nb = 0; nb < 8; ++nb) {
                bf16x8 vf = *(const bf16x8*)(Vt + vb + (size_t)nb * 16 * 2048 + ks * 32);
                acc[nb] = __builtin_amdgcn_mfma_f32_16x16x32_bf16(pf, vf, acc[nb], 0, 0, 0);
            }
        }
    }

    float inv[4];
#pragma unroll
    for (int reg = 0; reg < 4; ++reg) inv[reg] = 1.f / lreg[reg];
#pragma unroll
    for (int nb = 0; nb < 8; ++nb)
#pragma unroll
        for (int reg = 0; reg < 4; ++reg)
            attno[((size_t)(b * 2048 + qrow + 4 * g + reg) * 16 + h) * 128 + nb * 16 + c16] =
                f2bf(acc[nb][reg] * inv[reg]);
}

// ---------------------------------------------------------------------------
extern "C" void kernel_launch(void* const* d_in, const int* in_sizes, int n_in,
                              void* d_out, int out_size, void* d_ws, size_t ws_size,
                              hipStream_t stream) {
    const float* hidden = (const float*)d_in[0];
    const float* cosT   = (const float*)d_in[1];
    const float* sinT   = (const float*)d_in[2];
    const int*   pid    = (const int*)d_in[3];
    const float* Wq     = (const float*)d_in[4];
    const float* Wkv_a  = (const float*)d_in[5];
    const float* ln_g   = (const float*)d_in[6];
    const float* ln_b   = (const float*)d_in[7];
    const float* Wkv_b  = (const float*)d_in[8];
    const float* Wo     = (const float*)d_in[9];
    float* out = (float*)d_out;

    char* p = (char*)d_ws;
    short* hid_bf = (short*)p;               p += (size_t)NTOK * 2048 * 2;       // 16.78M
    short* WqT    = (short*)p;               p += (size_t)3072 * 2048 * 2;       // 12.58M
    short* WkaT   = (short*)p;               p += (size_t)640 * 2048 * 2;        //  2.62M
    short* WkbT   = (short*)p;               p += (size_t)4096 * 512 * 2;        //  4.19M
    short* WoT    = (short*)p;               p += (size_t)2048 * 2048 * 2;       //  8.39M
    char*  big    = p;                       p += (size_t)NTOK * 3072 * 4;       // 50.33M (qf32; later ckv/Vt/attno)
    short* qbuf   = (short*)p;               p += (size_t)NTOK * 3072 * 2;       // 25.17M
    short* kvcn   = (short*)p;               p += (size_t)NTOK * 512 * 2;        //  4.19M
    short* kpe    = (short*)p;               p += (size_t)NTOK * 64 * 2;         //  0.52M
    short* kvb    = (short*)p;               p += (size_t)NTOK * 4096 * 2;       // 33.55M

    float* qf32  = (float*)big;
    float* ckv   = (float*)big;                                   // reuse after q consumed
    short* Vt    = (short*)(big + (size_t)NTOK * 640 * 4);        // 16.78M after ckv
    short* attno = (short*)(big + (size_t)NTOK * 640 * 4 + (size_t)2 * 16 * 128 * 2048 * 2);

    // --- casts / transposes ---
    castk<<<8192, 256, 0, stream>>>(hidden, hid_bf);                               // 8.4M elems
    transpose_cast<<<dim3(96, 64), 256, 0, stream>>>(Wq, WqT, 2048, 3072);
    transpose_cast<<<dim3(20, 64), 256, 0, stream>>>(Wkv_a, WkaT, 2048, 576);      // pad to 640
    transpose_cast<<<dim3(128, 16), 256, 0, stream>>>(Wkv_b, WkbT, 512, 4096);
    transpose_cast<<<dim3(64, 64), 256, 0, stream>>>(Wo, WoT, 2048, 2048);

    // 1. q = hidden @ Wq (f32 out)
    gemm_mfma<0><<<dim3(24, 32), 256, 0, stream>>>(hid_bf, WqT, qf32, 4096, 3072, 2048);
    // 2. RoPE + cast q -> bf16
    rope_cast_q<<<NTOK, 256, 0, stream>>>(qf32, qbuf, cosT, sinT, pid);
    // 3. ckv = hidden @ Wkv_a (N padded to 640, f32 out; overwrites qf32 region)
    gemm_mfma<0><<<dim3(5, 32), 256, 0, stream>>>(hid_bf, WkaT, ckv, 4096, 640, 2048);
    // 4. LayerNorm + RoPE(k_pe) -> bf16
    ln_rope<<<NTOK, 256, 0, stream>>>(ckv, ln_g, ln_b, cosT, sinT, pid, kvcn, kpe);
    // 5. kv = kvcn @ Wkv_b (bf16 out)
    gemm_mfma<1><<<dim3(32, 32), 256, 0, stream>>>(kvcn, WkbT, kvb, 4096, 4096, 512);
    // 6. V transpose for PV fragments
    transpose_v<<<dim3(32, 2, 32), 256, 0, stream>>>(kvb, Vt);
    // 7. flash attention (bf16 MFMA)
    flash_mfma<<<dim3(32, 16, 2), 256, 0, stream>>>(qbuf, kvb, kpe, Vt, attno);
    // 8. out = attno @ Wo (f32 out)
    gemm_mfma<0><<<dim3(16, 32), 256, 0, stream>>>(attno, WoT, out, 4096, 2048, 2048);
}

// Round 4
// 428.670 us; speedup vs baseline: 11.6627x; 2.2592x over previous
//
#include <hip/hip_runtime.h>
#include <math.h>
#include <stdint.h>

#define B_      2
#define S_      2048
#define HID_    2048
#define H_      16
#define D_NOPE_ 128
#define D_ROPE_ 64
#define D_V_    128
#define R_      512
#define D_Q_    192
#define NTOK    (B_ * S_)
#define EPS_    1e-6f

typedef __attribute__((ext_vector_type(8))) short bf16x8;
typedef __attribute__((ext_vector_type(4))) float f32x4;

__device__ __forceinline__ short f2bf(float x) {
    union { float f; unsigned u; } un; un.f = x;
    unsigned r = (un.u + 0x7fffu + ((un.u >> 16) & 1u)) >> 16;
    return (short)r;
}

__device__ __forceinline__ void async_ld16(const short* gsrc, short* ldst) {
    __builtin_amdgcn_global_load_lds(
        (const __attribute__((address_space(1))) void*)gsrc,
        (__attribute__((address_space(3))) void*)ldst, 16, 0, 0);
}

// ---------------------------------------------------------------------------
// cast f32 -> bf16
// ---------------------------------------------------------------------------
__global__ __launch_bounds__(256) void castk(const float* __restrict__ in, short* __restrict__ out) {
    int i = blockIdx.x * 256 + threadIdx.x;
    float4 v = ((const float4*)in)[i];
    ushort4 o;
    o.x = (unsigned short)f2bf(v.x); o.y = (unsigned short)f2bf(v.y);
    o.z = (unsigned short)f2bf(v.z); o.w = (unsigned short)f2bf(v.w);
    ((ushort4*)out)[i] = o;
}

// ---------------------------------------------------------------------------
// W[K][Nreal] f32 -> WT[Npad][K] bf16 (rows >= Nreal zero-filled).
// ---------------------------------------------------------------------------
__global__ __launch_bounds__(256) void transpose_cast(const float* __restrict__ W,
                                                      short* __restrict__ WT,
                                                      int K, int Nreal) {
    __shared__ float T[32][33];
    const int n0 = blockIdx.x * 32, k0 = blockIdx.y * 32;
    const int t = threadIdx.x;
    const int r = t >> 3, c4 = (t & 7) * 4;
    float4 v = make_float4(0.f, 0.f, 0.f, 0.f);
    if (n0 < Nreal) v = *(const float4*)&W[(size_t)(k0 + r) * Nreal + n0 + c4];
    T[r][c4 + 0] = v.x; T[r][c4 + 1] = v.y; T[r][c4 + 2] = v.z; T[r][c4 + 3] = v.w;
    __syncthreads();
    const int n = t >> 3, k4 = (t & 7) * 4;
    ushort4 o;
    o.x = (unsigned short)f2bf(T[k4 + 0][n]);
    o.y = (unsigned short)f2bf(T[k4 + 1][n]);
    o.z = (unsigned short)f2bf(T[k4 + 2][n]);
    o.w = (unsigned short)f2bf(T[k4 + 3][n]);
    *(ushort4*)&WT[(size_t)(n0 + n) * K + k0 + k4] = o;
}

// ---------------------------------------------------------------------------
// MFMA GEMM: C[M][N] = A[M][K](bf16) @ BT[N][K](bf16). 128x128 tile, 4 waves.
// ---------------------------------------------------------------------------
template <int OUTBF>
__global__ __launch_bounds__(256) void gemm_mfma(const short* __restrict__ A,
                                                 const short* __restrict__ BT,
                                                 void* __restrict__ C,
                                                 int M, int N, int K) {
    __shared__ short As[128 * 32];
    __shared__ short Bs[128 * 32];
    const int tid = threadIdx.x;
    const int lane = tid & 63, w = tid >> 6;
    const int brow = blockIdx.y * 128, bcol = blockIdx.x * 128;

    const int o0 = w * 1024 + lane * 16;
    const int r0 = o0 >> 6, q0p = (o0 >> 4) & 3;
    const int o1 = o0 + 4096;
    const int r1 = o1 >> 6, q1p = (o1 >> 4) & 3;
    const int s0 = r0 * K + 8 * (q0p ^ ((r0 >> 1) & 3));
    const int s1 = r1 * K + 8 * (q1p ^ ((r1 >> 1) & 3));
    const short* Ab = A + (size_t)brow * K;
    const short* Bb = BT + (size_t)bcol * K;
    short* AsU0 = &As[w * 512]; short* AsU1 = &As[w * 512 + 2048];
    short* BsU0 = &Bs[w * 512]; short* BsU1 = &Bs[w * 512 + 2048];

    const int wr = w >> 1, wc = w & 1;
    const int c16 = lane & 15, g = lane >> 4;
    const int qph = (g ^ ((c16 >> 1) & 3)) * 8;

    f32x4 zero = {0.f, 0.f, 0.f, 0.f};
    f32x4 acc[4][4];
#pragma unroll
    for (int i = 0; i < 4; ++i)
#pragma unroll
        for (int j = 0; j < 4; ++j) acc[i][j] = zero;

    for (int k0 = 0; k0 < K; k0 += 32) {
        async_ld16(Ab + s0 + k0, AsU0);
        async_ld16(Ab + s1 + k0, AsU1);
        async_ld16(Bb + s0 + k0, BsU0);
        async_ld16(Bb + s1 + k0, BsU1);
        __syncthreads();
        bf16x8 af[4], bf[4];
#pragma unroll
        for (int i = 0; i < 4; ++i) {
            af[i] = *(const bf16x8*)&As[(wr * 64 + i * 16 + c16) * 32 + qph];
            bf[i] = *(const bf16x8*)&Bs[(wc * 64 + i * 16 + c16) * 32 + qph];
        }
#pragma unroll
        for (int mi = 0; mi < 4; ++mi)
#pragma unroll
            for (int ni = 0; ni < 4; ++ni)
                acc[mi][ni] = __builtin_amdgcn_mfma_f32_16x16x32_bf16(af[mi], bf[ni], acc[mi][ni], 0, 0, 0);
        __syncthreads();
    }

#pragma unroll
    for (int mi = 0; mi < 4; ++mi)
#pragma unroll
        for (int ni = 0; ni < 4; ++ni)
#pragma unroll
            for (int reg = 0; reg < 4; ++reg) {
                int row = brow + wr * 64 + mi * 16 + 4 * g + reg;
                int col = bcol + wc * 64 + ni * 16 + c16;
                if (OUTBF) ((short*)C)[(size_t)row * N + col] = f2bf(acc[mi][ni][reg]);
                else       ((float*)C)[(size_t)row * N + col] = acc[mi][ni][reg];
            }
}

// ---------------------------------------------------------------------------
// RoPE q_pe + cast all of q to bf16. One block per token.
// ---------------------------------------------------------------------------
__global__ __launch_bounds__(256) void rope_cast_q(const float* __restrict__ q,
                                                   short* __restrict__ qb,
                                                   const float* __restrict__ cosT,
                                                   const float* __restrict__ sinT,
                                                   const int* __restrict__ pid) {
    const int tok = blockIdx.x, t = threadIdx.x;
    const float* src = q + (size_t)tok * 3072;
    short* dst = qb + (size_t)tok * 3072;
    {
        int h = t >> 4, d0 = (t & 15) * 8;
        const float* s1 = src + h * 192 + d0;
        float4 a = *(const float4*)s1;
        float4 b = *(const float4*)(s1 + 4);
        ushort4 o1, o2;
        o1.x = (unsigned short)f2bf(a.x); o1.y = (unsigned short)f2bf(a.y);
        o1.z = (unsigned short)f2bf(a.z); o1.w = (unsigned short)f2bf(a.w);
        o2.x = (unsigned short)f2bf(b.x); o2.y = (unsigned short)f2bf(b.y);
        o2.z = (unsigned short)f2bf(b.z); o2.w = (unsigned short)f2bf(b.w);
        *(ushort4*)(dst + h * 192 + d0) = o1;
        *(ushort4*)(dst + h * 192 + d0 + 4) = o2;
    }
    const int pos = pid[tok];
#pragma unroll
    for (int pp = 0; pp < 2; ++pp) {
        int p = t * 2 + pp;
        int h2 = p >> 5, i = p & 31;
        float cc = cosT[pos * 32 + i], ss = sinT[pos * 32 + i];
        float x1 = src[h2 * 192 + 128 + i], x2 = src[h2 * 192 + 160 + i];
        dst[h2 * 192 + 128 + i] = f2bf(x1 * cc - x2 * ss);
        dst[h2 * 192 + 160 + i] = f2bf(x2 * cc + x1 * ss);
    }
}

// ---------------------------------------------------------------------------
// LayerNorm(512) + RoPE(k_pe). ckv stride 640. Outputs bf16.
// ---------------------------------------------------------------------------
__global__ __launch_bounds__(256) void ln_rope(const float* __restrict__ ckv,
                                               const float* __restrict__ gam,
                                               const float* __restrict__ bet,
                                               const float* __restrict__ cosT,
                                               const float* __restrict__ sinT,
                                               const int* __restrict__ pid,
                                               short* __restrict__ kvcn,
                                               short* __restrict__ kpe) {
    const int tok = blockIdx.x, tid = threadIdx.x;
    const float* x = ckv + (size_t)tok * 640;
    float v0 = x[tid], v1 = x[tid + 256];
    float s = v0 + v1, sq = v0 * v0 + v1 * v1;
#pragma unroll
    for (int m = 1; m < 64; m <<= 1) { s += __shfl_xor(s, m); sq += __shfl_xor(sq, m); }
    __shared__ float ws[8];
    int wid = tid >> 6, lane = tid & 63;
    if (lane == 0) { ws[wid] = s; ws[4 + wid] = sq; }
    __syncthreads();
    s = ws[0] + ws[1] + ws[2] + ws[3];
    sq = ws[4] + ws[5] + ws[6] + ws[7];
    float mean = s * (1.f / 512.f);
    float var = sq * (1.f / 512.f) - mean * mean;
    float rstd = rsqrtf(var + EPS_);
    kvcn[(size_t)tok * 512 + tid]       = f2bf((v0 - mean) * rstd * gam[tid] + bet[tid]);
    kvcn[(size_t)tok * 512 + tid + 256] = f2bf((v1 - mean) * rstd * gam[tid + 256] + bet[tid + 256]);
    if (tid < 32) {
        int pos = pid[tok];
        float c = cosT[pos * 32 + tid], sn = sinT[pos * 32 + tid];
        float x1 = x[512 + tid], x2 = x[512 + 32 + tid];
        kpe[(size_t)tok * 64 + tid]      = f2bf(x1 * c - x2 * sn);
        kpe[(size_t)tok * 64 + 32 + tid] = f2bf(x2 * c + x1 * sn);
    }
}

// ---------------------------------------------------------------------------
// V transpose: kvb[token][h][128..255] -> Vt[b][h][d][s].
// ---------------------------------------------------------------------------
__global__ __launch_bounds__(256) void transpose_v(const short* __restrict__ kvb,
                                                   short* __restrict__ Vt) {
    __shared__ short T[64][72];
    const int s0 = blockIdx.x * 64, d0 = blockIdx.y * 64, bh = blockIdx.z;
    const int b = bh >> 4, h = bh & 15;
    const int t = threadIdx.x;
    const int r = t >> 3, c8 = (t & 7) * 8;
#pragma unroll
    for (int i = 0; i < 2; ++i) {
        int rr = r + 32 * i;
        bf16x8 v = *(const bf16x8*)&kvb[((size_t)(b * 2048 + s0 + rr) * 16 + h) * 256 + 128 + d0 + c8];
        *(bf16x8*)&T[rr][c8] = v;
    }
    __syncthreads();
#pragma unroll
    for (int i = 0; i < 2; ++i) {
        int d = r + 32 * i;
        bf16x8 o;
#pragma unroll
        for (int j = 0; j < 8; ++j) o[j] = T[c8 + j][d];
        *(bf16x8*)&Vt[((size_t)(b * 16 + h) * 128 + d0 + d) * 2048 + s0 + c8] = o;
    }
}

// ---------------------------------------------------------------------------
// MFMA flash attention, LDS-staged K/V with 2-phase double-buffer.
// Grid: 1024 blocks 1-D, XCD-aware mapping. Block = 64 q-rows, 4 waves.
// LDS layout (both tiles chunk-swizzled: 16B slot q holds source chunk
// q^(row&7); staged via inverse-swizzled global source, rule 21):
//   Ks[buf][64 rows][128 shorts]  (K nope, row = token)
//   Vs[buf][128 rows][64 shorts]  (V^T, row = d, cols = tokens)
// ---------------------------------------------------------------------------
__global__ __launch_bounds__(256) void flash_mfma(const short* __restrict__ qb,
                                                  const short* __restrict__ kvb,
                                                  const short* __restrict__ kpe,
                                                  const short* __restrict__ Vt,
                                                  short* __restrict__ attno) {
    __shared__ short Ks[2][64 * 128];
    __shared__ short Vs[2][128 * 64];
    __shared__ short P[4][16][72];

    // XCD-aware mapping: all q-tiles of a (b,h) on one XCD; long blocks first.
    const int flat = blockIdx.x;
    const int xcd = flat & 7, idx = flat >> 3;
    const int bh = xcd + 8 * (idx >> 5);
    const int qt = 31 - (idx & 31);
    const int b = bh >> 4, h = bh & 15;
    const int q0 = qt * 64;

    const int tid = threadIdx.x, lane = tid & 63, w = tid >> 6;
    const int c16 = lane & 15, g = lane >> 4, g8 = g * 8;
    const float scale = 0.07216878364870323f;   // 1/sqrt(192)

    const int qrow = q0 + w * 16;
    const size_t qbase = ((size_t)(b * 2048 + qrow + c16) * 16 + h) * 192 + g8;
    bf16x8 qf[6];
#pragma unroll
    for (int ks = 0; ks < 6; ++ks) qf[ks] = *(const bf16x8*)(qb + qbase + 32 * ks);

    f32x4 zero = {0.f, 0.f, 0.f, 0.f};
    f32x4 acc[8];
#pragma unroll
    for (int i = 0; i < 8; ++i) acc[i] = zero;
    float mreg[4] = {-INFINITY, -INFINITY, -INFINITY, -INFINITY};
    float lreg[4] = {0.f, 0.f, 0.f, 0.f};

    // ---- staging lambda-equivalent (macro to keep addresses static) ----
#define STAGE_TILES(BUF, K0)                                                          \
    {                                                                                 \
        _Pragma("unroll")                                                             \
        for (int rnd = 0; rnd < 4; ++rnd) {                                           \
            int o = rnd * 4096 + w * 1024 + lane * 16;                                \
            int r = o >> 8, qs = (o >> 4) & 15;                                       \
            int cc = qs ^ (r & 7);                                                    \
            const short* src = kvb + ((size_t)((b * 2048 + (K0) + r) * 16 + h)) * 256 \
                               + cc * 8;                                              \
            async_ld16(src, &Ks[BUF][(rnd * 4096 + w * 1024) >> 1]);                  \
        }                                                                             \
        _Pragma("unroll")                                                             \
        for (int rnd = 0; rnd < 4; ++rnd) {                                           \
            int o = rnd * 4096 + w * 1024 + lane * 16;                                \
            int r = o >> 7, qs = (o >> 4) & 7;                                        \
            int cc = qs ^ (r & 7);                                                    \
            const short* src = Vt + ((size_t)((b * 16 + h) * 128 + r)) * 2048 + (K0)  \
                               + cc * 8;                                              \
            async_ld16(src, &Vs[BUF][(rnd * 4096 + w * 1024) >> 1]);                  \
        }                                                                             \
    }

    const int nt = qt + 1;
    STAGE_TILES(0, 0);
    __syncthreads();
    int cur = 0;

    for (int kt = 0; kt < nt; ++kt) {
        const int k0 = kt * 64;
        if (kt + 1 < nt) STAGE_TILES(cur ^ 1, k0 + 64);

        f32x4 sc[4];
#pragma unroll
        for (int i = 0; i < 4; ++i) sc[i] = zero;

        // QK^T nope from LDS (swizzled reads)
#pragma unroll
        for (int ks = 0; ks < 4; ++ks)
#pragma unroll
            for (int nb = 0; nb < 4; ++nb) {
                int row = nb * 16 + c16;
                bf16x8 kf = *(const bf16x8*)&Ks[cur][row * 128 + (((g + 4 * ks) ^ (row & 7)) << 3)];
                sc[nb] = __builtin_amdgcn_mfma_f32_16x16x32_bf16(qf[ks], kf, sc[nb], 0, 0, 0);
            }
        // pe part straight from global (kpe is tiny + shared across heads -> L2-hot)
        const size_t pb = (size_t)(b * 2048 + k0 + c16) * 64 + g8;
#pragma unroll
        for (int ks = 0; ks < 2; ++ks)
#pragma unroll
            for (int nb = 0; nb < 4; ++nb) {
                bf16x8 kf = *(const bf16x8*)(kpe + pb + (size_t)nb * 16 * 64 + ks * 32);
                sc[nb] = __builtin_amdgcn_mfma_f32_16x16x32_bf16(qf[4 + ks], kf, sc[nb], 0, 0, 0);
            }

#pragma unroll
        for (int nb = 0; nb < 4; ++nb) sc[nb] *= scale;

        if (kt == nt - 1) {
#pragma unroll
            for (int nb = 0; nb < 4; ++nb)
#pragma unroll
                for (int reg = 0; reg < 4; ++reg) {
                    int col = k0 + nb * 16 + c16;
                    int row = qrow + 4 * g + reg;
                    if (col > row) sc[nb][reg] = -INFINITY;
                }
        }

        // online softmax
        float rmax[4], rsum[4], mnew[4], alpha[4];
#pragma unroll
        for (int reg = 0; reg < 4; ++reg)
            rmax[reg] = fmaxf(fmaxf(sc[0][reg], sc[1][reg]), fmaxf(sc[2][reg], sc[3][reg]));
#pragma unroll
        for (int m = 1; m < 16; m <<= 1)
#pragma unroll
            for (int reg = 0; reg < 4; ++reg)
                rmax[reg] = fmaxf(rmax[reg], __shfl_xor(rmax[reg], m));
#pragma unroll
        for (int reg = 0; reg < 4; ++reg) {
            mnew[reg] = fmaxf(mreg[reg], rmax[reg]);
            alpha[reg] = __expf(mreg[reg] - mnew[reg]);
            mreg[reg] = mnew[reg];
            rsum[reg] = 0.f;
        }
#pragma unroll
        for (int nb = 0; nb < 4; ++nb)
#pragma unroll
            for (int reg = 0; reg < 4; ++reg) {
                float p = __expf(sc[nb][reg] - mnew[reg]);
                sc[nb][reg] = p;
                rsum[reg] += p;
            }
#pragma unroll
        for (int m = 1; m < 16; m <<= 1)
#pragma unroll
            for (int reg = 0; reg < 4; ++reg)
                rsum[reg] += __shfl_xor(rsum[reg], m);
#pragma unroll
        for (int reg = 0; reg < 4; ++reg) lreg[reg] = lreg[reg] * alpha[reg] + rsum[reg];
#pragma unroll
        for (int nb = 0; nb < 8; ++nb)
#pragma unroll
            for (int reg = 0; reg < 4; ++reg) acc[nb][reg] *= alpha[reg];

        // P -> LDS (C/D layout -> A layout)
#pragma unroll
        for (int nb = 0; nb < 4; ++nb)
#pragma unroll
            for (int reg = 0; reg < 4; ++reg)
                P[w][4 * g + reg][nb * 16 + c16] = f2bf(sc[nb][reg]);

        // PV from LDS V (swizzled reads)
#pragma unroll
        for (int ks = 0; ks < 2; ++ks) {
            bf16x8 pf = *(const bf16x8*)&P[w][c16][ks * 32 + g8];
#pragma unroll
            for (int nb = 0; nb < 8; ++nb) {
                int row = nb * 16 + c16;
                bf16x8 vf = *(const bf16x8*)&Vs[cur][row * 64 + (((g + 4 * ks) ^ (row & 7)) << 3)];
                acc[nb] = __builtin_amdgcn_mfma_f32_16x16x32_bf16(pf, vf, acc[nb], 0, 0, 0);
            }
        }

        __syncthreads();   // drains stage vmcnt + all waves done with buffers
        cur ^= 1;
    }
#undef STAGE_TILES

    float inv[4];
#pragma unroll
    for (int reg = 0; reg < 4; ++reg) inv[reg] = 1.f / lreg[reg];
#pragma unroll
    for (int nb = 0; nb < 8; ++nb)
#pragma unroll
        for (int reg = 0; reg < 4; ++reg)
            attno[((size_t)(b * 2048 + qrow + 4 * g + reg) * 16 + h) * 128 + nb * 16 + c16] =
                f2bf(acc[nb][reg] * inv[reg]);
}

// ---------------------------------------------------------------------------
extern "C" void kernel_launch(void* const* d_in, const int* in_sizes, int n_in,
                              void* d_out, int out_size, void* d_ws, size_t ws_size,
                              hipStream_t stream) {
    const float* hidden = (const float*)d_in[0];
    const float* cosT   = (const float*)d_in[1];
    const float* sinT   = (const float*)d_in[2];
    const int*   pid    = (const int*)d_in[3];
    const float* Wq     = (const float*)d_in[4];
    const float* Wkv_a  = (const float*)d_in[5];
    const float* ln_g   = (const float*)d_in[6];
    const float* ln_b   = (const float*)d_in[7];
    const float* Wkv_b  = (const float*)d_in[8];
    const float* Wo     = (const float*)d_in[9];
    float* out = (float*)d_out;

    char* p = (char*)d_ws;
    short* hid_bf = (short*)p;               p += (size_t)NTOK * 2048 * 2;
    short* WqT    = (short*)p;               p += (size_t)3072 * 2048 * 2;
    short* WkaT   = (short*)p;               p += (size_t)640 * 2048 * 2;
    short* WkbT   = (short*)p;               p += (size_t)4096 * 512 * 2;
    short* WoT    = (short*)p;               p += (size_t)2048 * 2048 * 2;
    char*  big    = p;                       p += (size_t)NTOK * 3072 * 4;
    short* qbuf   = (short*)p;               p += (size_t)NTOK * 3072 * 2;
    short* kvcn   = (short*)p;               p += (size_t)NTOK * 512 * 2;
    short* kpe    = (short*)p;               p += (size_t)NTOK * 64 * 2;
    short* kvb    = (short*)p;               p += (size_t)NTOK * 4096 * 2;

    float* qf32  = (float*)big;
    float* ckv   = (float*)big;
    short* Vt    = (short*)(big + (size_t)NTOK * 640 * 4);
    short* attno = (short*)(big + (size_t)NTOK * 640 * 4 + (size_t)2 * 16 * 128 * 2048 * 2);

    castk<<<8192, 256, 0, stream>>>(hidden, hid_bf);
    transpose_cast<<<dim3(96, 64), 256, 0, stream>>>(Wq, WqT, 2048, 3072);
    transpose_cast<<<dim3(20, 64), 256, 0, stream>>>(Wkv_a, WkaT, 2048, 576);
    transpose_cast<<<dim3(128, 16), 256, 0, stream>>>(Wkv_b, WkbT, 512, 4096);
    transpose_cast<<<dim3(64, 64), 256, 0, stream>>>(Wo, WoT, 2048, 2048);

    gemm_mfma<0><<<dim3(24, 32), 256, 0, stream>>>(hid_bf, WqT, qf32, 4096, 3072, 2048);
    rope_cast_q<<<NTOK, 256, 0, stream>>>(qf32, qbuf, cosT, sinT, pid);
    gemm_mfma<0><<<dim3(5, 32), 256, 0, stream>>>(hid_bf, WkaT, ckv, 4096, 640, 2048);
    ln_rope<<<NTOK, 256, 0, stream>>>(ckv, ln_g, ln_b, cosT, sinT, pid, kvcn, kpe);
    gemm_mfma<1><<<dim3(32, 32), 256, 0, stream>>>(kvcn, WkbT, kvb, 4096, 4096, 512);
    transpose_v<<<dim3(32, 2, 32), 256, 0, stream>>>(kvb, Vt);
    flash_mfma<<<1024, 256, 0, stream>>>(qbuf, kvb, kpe, Vt, attno);
    gemm_mfma<0><<<dim3(16, 32), 256, 0, stream>>>(attno, WoT, out, 4096, 2048, 2048);
}